// Round 1
// baseline (212.633 us; speedup 1.0000x reference)
//
#include <hip/hip_runtime.h>

// YOLO loss: preds (B,7,7,30) f32, labels (B,7,7,30) f32 -> scalar f32 (sum/B).
// Memory-bound: ~193 MB read per launch. One thread per (b,y,x) cell.

#define BATCH 16384
#define S 7
#define C 30
#define NCELLS (BATCH * S * S)   // 802816
#define BLOCK 256

__device__ __forceinline__ float sq(float v) { return v * v; }

__device__ __forceinline__ float iou_box(float acx, float acy, float aw, float ah,
                                         float bcx, float bcy, float bw, float bh) {
    float ax0 = acx - aw * 0.5f, ax1 = acx + aw * 0.5f;
    float ay0 = acy - ah * 0.5f, ay1 = acy + ah * 0.5f;
    float bx0 = bcx - bw * 0.5f, bx1 = bcx + bw * 0.5f;
    float by0 = bcy - bh * 0.5f, by1 = bcy + bh * 0.5f;
    float iw = fminf(ax1, bx1) - fmaxf(ax0, bx0);
    float ih = fminf(ay1, by1) - fmaxf(ay0, by0);
    iw = fmaxf(iw, 0.0f);
    ih = fmaxf(ih, 0.0f);
    float inter = iw * ih;
    float denom = aw * ah + bw * bh - inter + 1e-10f;
    return inter / denom;
}

__global__ __launch_bounds__(BLOCK) void yolo_loss_kernel(
        const float* __restrict__ preds,
        const float* __restrict__ labels,
        float* __restrict__ out) {
    int cell = blockIdx.x * BLOCK + threadIdx.x;
    float loss = 0.0f;
    if (cell < NCELLS) {
        const float* p = preds  + (size_t)cell * C;
        const float* l = labels + (size_t)cell * C;

        float pv[C], lv[C];
        #pragma unroll
        for (int i = 0; i < C / 2; ++i) {
            float2 tp = *reinterpret_cast<const float2*>(p + 2 * i);
            pv[2 * i] = tp.x; pv[2 * i + 1] = tp.y;
            float2 tl = *reinterpret_cast<const float2*>(l + 2 * i);
            lv[2 * i] = tl.x; lv[2 * i + 1] = tl.y;
        }

        // transposed label x-coord quirk: labels[b, x, y, 0]
        int b   = cell / (S * S);
        int rem = cell - b * (S * S);
        int y   = rem / S;
        int x   = rem - y * S;
        float lb0 = labels[((size_t)b * (S * S) + x * S + y) * C];

        float iou1 = iou_box(pv[0], pv[1], pv[2], pv[3], lb0, lv[1], lv[2], lv[3]);
        float iou2 = iou_box(pv[5], pv[6], pv[7], pv[8], lb0, lv[1], lv[2], lv[3]);

        float b1 = 5.0f * (sq(pv[0] - lv[0]) + sq(pv[1] - lv[1]))
                 + sq(sqrtf(pv[2]) - sqrtf(lv[2])) + sq(sqrtf(pv[3]) - sqrtf(lv[3]))
                 + sq(iou1 - pv[4])
                 + 0.5f * pv[9] * pv[9];

        float b2 = 5.0f * (sq(pv[5] - lv[5]) + sq(pv[6] - lv[6]))
                 + sq(sqrtf(pv[7]) - sqrtf(lv[7])) + sq(sqrtf(pv[8]) - sqrtf(lv[8]))
                 + sq(iou2 - pv[9])
                 + 0.5f * pv[4] * pv[4];

        float cls = 0.0f;
        #pragma unroll
        for (int c = 10; c < C; ++c) cls += sq(lv[c] - pv[c]);

        float obj_loss   = ((iou1 > iou2) ? b1 : b2) + cls;
        float noobj_loss = 0.5f * (pv[4] * pv[4] + pv[9] * pv[9]);

        loss = (lv[4] == 1.0f) ? obj_loss : noobj_loss;
    }

    // wave (64) shuffle reduce
    #pragma unroll
    for (int off = 32; off > 0; off >>= 1)
        loss += __shfl_down(loss, off, 64);

    __shared__ float wsum[BLOCK / 64];
    int lane = threadIdx.x & 63;
    int wv   = threadIdx.x >> 6;
    if (lane == 0) wsum[wv] = loss;
    __syncthreads();
    if (threadIdx.x == 0) {
        float s = wsum[0] + wsum[1] + wsum[2] + wsum[3];
        atomicAdd(out, s * (1.0f / (float)BATCH));
    }
}

extern "C" void kernel_launch(void* const* d_in, const int* in_sizes, int n_in,
                              void* d_out, int out_size, void* d_ws, size_t ws_size,
                              hipStream_t stream) {
    const float* preds  = (const float*)d_in[0];
    const float* labels = (const float*)d_in[1];
    float* out = (float*)d_out;

    // d_out is poisoned (0xAA) before every launch; zero it (capture-legal).
    hipMemsetAsync(out, 0, sizeof(float), stream);

    int grid = (NCELLS + BLOCK - 1) / BLOCK;  // 3136
    yolo_loss_kernel<<<grid, BLOCK, 0, stream>>>(preds, labels, out);
}

// Round 2
// 211.131 us; speedup vs baseline: 1.0071x; 1.0071x over previous
//
#include <hip/hip_runtime.h>

// YOLO loss: preds (B,7,7,30) f32, labels (B,7,7,30) f32 -> scalar f32 (sum/B).
// Memory-bound (~193 MB/launch). R2: coalesced float4 global loads -> LDS
// staging -> per-cell compute. One block = 256 cells.

#define BATCH 16384
#define S 7
#define C 30
#define NCELLS (BATCH * S * S)   // 802816
#define BLOCK 256
#define NC 256                    // cells per block
#define F4_PER_ARR (NC * C / 4)   // 1920 float4 per array per block

__device__ __forceinline__ float sq(float v) { return v * v; }

__device__ __forceinline__ float iou_box(float acx, float acy, float aw, float ah,
                                         float bcx, float bcy, float bw, float bh) {
    float ax0 = acx - aw * 0.5f, ax1 = acx + aw * 0.5f;
    float ay0 = acy - ah * 0.5f, ay1 = acy + ah * 0.5f;
    float bx0 = bcx - bw * 0.5f, bx1 = bcx + bw * 0.5f;
    float by0 = bcy - bh * 0.5f, by1 = bcy + bh * 0.5f;
    float iw = fmaxf(fminf(ax1, bx1) - fmaxf(ax0, bx0), 0.0f);
    float ih = fmaxf(fminf(ay1, by1) - fmaxf(ay0, by0), 0.0f);
    float inter = iw * ih;
    float denom = aw * ah + bw * bh - inter + 1e-10f;
    return inter / denom;
}

__global__ __launch_bounds__(BLOCK) void yolo_loss_kernel(
        const float* __restrict__ preds,
        const float* __restrict__ labels,
        float* __restrict__ out) {
    __shared__ float sp[NC * C];   // 30720 B
    __shared__ float sl[NC * C];   // 30720 B

    const int tid = threadIdx.x;
    const int base_cell = blockIdx.x * NC;  // block byte base = 30720*blockIdx -> 16B aligned

    // ---- coalesced global -> LDS staging (float4, lane-contiguous) ----
    const float4* gp = reinterpret_cast<const float4*>(preds  + (size_t)base_cell * C);
    const float4* gl = reinterpret_cast<const float4*>(labels + (size_t)base_cell * C);
    float4* s4p = reinterpret_cast<float4*>(sp);
    float4* s4l = reinterpret_cast<float4*>(sl);
    #pragma unroll
    for (int k = 0; k < 8; ++k) {
        int idx = k * BLOCK + tid;            // 1920 = 7*256 + 128
        if (idx < F4_PER_ARR) {
            s4p[idx] = gp[idx];
            s4l[idx] = gl[idx];
        }
    }
    __syncthreads();

    // ---- per-cell compute from LDS ----
    const float* p = sp + tid * C;  // tid*30 even -> 8B aligned
    const float* l = sl + tid * C;
    float pv[C], lv[C];
    #pragma unroll
    for (int i = 0; i < C / 2; ++i) {
        float2 tp = *reinterpret_cast<const float2*>(p + 2 * i);
        pv[2 * i] = tp.x; pv[2 * i + 1] = tp.y;
        float2 tl = *reinterpret_cast<const float2*>(l + 2 * i);
        lv[2 * i] = tl.x; lv[2 * i + 1] = tl.y;
    }

    // transposed label x-coord quirk: labels[b, x, y, 0]
    int cell = base_cell + tid;
    int b    = cell / (S * S);
    int rem  = cell - b * (S * S);
    int y    = rem / S;
    int x    = rem - y * S;
    int pc   = b * (S * S) + x * S + y;       // partner cell index
    float lb0;
    if (pc >= base_cell && pc < base_cell + NC) {
        lb0 = sl[(pc - base_cell) * C];
    } else {
        lb0 = labels[(size_t)pc * C];         // rare: image straddles block edge
    }

    float iou1 = iou_box(pv[0], pv[1], pv[2], pv[3], lb0, lv[1], lv[2], lv[3]);
    float iou2 = iou_box(pv[5], pv[6], pv[7], pv[8], lb0, lv[1], lv[2], lv[3]);

    float b1 = 5.0f * (sq(pv[0] - lv[0]) + sq(pv[1] - lv[1]))
             + sq(sqrtf(pv[2]) - sqrtf(lv[2])) + sq(sqrtf(pv[3]) - sqrtf(lv[3]))
             + sq(iou1 - pv[4])
             + 0.5f * pv[9] * pv[9];

    float b2 = 5.0f * (sq(pv[5] - lv[5]) + sq(pv[6] - lv[6]))
             + sq(sqrtf(pv[7]) - sqrtf(lv[7])) + sq(sqrtf(pv[8]) - sqrtf(lv[8]))
             + sq(iou2 - pv[9])
             + 0.5f * pv[4] * pv[4];

    float cls = 0.0f;
    #pragma unroll
    for (int c = 10; c < C; ++c) cls += sq(lv[c] - pv[c]);

    float obj_loss   = ((iou1 > iou2) ? b1 : b2) + cls;
    float noobj_loss = 0.5f * (pv[4] * pv[4] + pv[9] * pv[9]);
    float loss = (lv[4] == 1.0f) ? obj_loss : noobj_loss;

    // ---- reduction: wave shuffle -> LDS -> one atomic per block ----
    #pragma unroll
    for (int off = 32; off > 0; off >>= 1)
        loss += __shfl_down(loss, off, 64);

    __shared__ float wsum[BLOCK / 64];
    int lane = tid & 63;
    int wv   = tid >> 6;
    if (lane == 0) wsum[wv] = loss;
    __syncthreads();
    if (tid == 0) {
        float s = wsum[0] + wsum[1] + wsum[2] + wsum[3];
        atomicAdd(out, s * (1.0f / (float)BATCH));
    }
}

extern "C" void kernel_launch(void* const* d_in, const int* in_sizes, int n_in,
                              void* d_out, int out_size, void* d_ws, size_t ws_size,
                              hipStream_t stream) {
    const float* preds  = (const float*)d_in[0];
    const float* labels = (const float*)d_in[1];
    float* out = (float*)d_out;

    hipMemsetAsync(out, 0, sizeof(float), stream);

    int grid = NCELLS / NC;  // 3136, exact
    yolo_loss_kernel<<<grid, BLOCK, 0, stream>>>(preds, labels, out);
}

// Round 3
// 208.936 us; speedup vs baseline: 1.0177x; 1.0105x over previous
//
#include <hip/hip_runtime.h>

// YOLO loss: preds (B,7,7,30) f32, labels (B,7,7,30) f32 -> scalar f32 (sum/B).
// R3: remove single-address atomicAdd (theory: 3136 serialized device-scope
// atomics to one line = the constant 78us floor). Two-stage reduction:
//   k1: per-block partial -> d_ws[blockIdx]   (coalesced store, no contention)
//   k2: single block reduces 3136 partials -> d_out

#define BATCH 16384
#define S 7
#define C 30
#define NCELLS (BATCH * S * S)   // 802816
#define BLOCK 256
#define NC 256                    // cells per block
#define NBLK (NCELLS / NC)        // 3136
#define F4_PER_ARR (NC * C / 4)   // 1920 float4 per array per block

__device__ __forceinline__ float sq(float v) { return v * v; }

__device__ __forceinline__ float iou_box(float acx, float acy, float aw, float ah,
                                         float bcx, float bcy, float bw, float bh) {
    float ax0 = acx - aw * 0.5f, ax1 = acx + aw * 0.5f;
    float ay0 = acy - ah * 0.5f, ay1 = acy + ah * 0.5f;
    float bx0 = bcx - bw * 0.5f, bx1 = bcx + bw * 0.5f;
    float by0 = bcy - bh * 0.5f, by1 = bcy + bh * 0.5f;
    float iw = fmaxf(fminf(ax1, bx1) - fmaxf(ax0, bx0), 0.0f);
    float ih = fmaxf(fminf(ay1, by1) - fmaxf(ay0, by0), 0.0f);
    float inter = iw * ih;
    float denom = aw * ah + bw * bh - inter + 1e-10f;
    return inter / denom;
}

__global__ __launch_bounds__(BLOCK) void yolo_partial_kernel(
        const float* __restrict__ preds,
        const float* __restrict__ labels,
        float* __restrict__ partials) {
    __shared__ float sp[NC * C];   // 30720 B
    __shared__ float sl[NC * C];   // 30720 B

    const int tid = threadIdx.x;
    const int base_cell = blockIdx.x * NC;

    // ---- coalesced global -> LDS staging (float4, lane-contiguous) ----
    const float4* gp = reinterpret_cast<const float4*>(preds  + (size_t)base_cell * C);
    const float4* gl = reinterpret_cast<const float4*>(labels + (size_t)base_cell * C);
    float4* s4p = reinterpret_cast<float4*>(sp);
    float4* s4l = reinterpret_cast<float4*>(sl);
    #pragma unroll
    for (int k = 0; k < 8; ++k) {
        int idx = k * BLOCK + tid;            // 1920 = 7*256 + 128
        if (idx < F4_PER_ARR) {
            s4p[idx] = gp[idx];
            s4l[idx] = gl[idx];
        }
    }
    __syncthreads();

    // ---- per-cell compute from LDS ----
    const float* p = sp + tid * C;
    const float* l = sl + tid * C;
    float pv[C], lv[C];
    #pragma unroll
    for (int i = 0; i < C / 2; ++i) {
        float2 tp = *reinterpret_cast<const float2*>(p + 2 * i);
        pv[2 * i] = tp.x; pv[2 * i + 1] = tp.y;
        float2 tl = *reinterpret_cast<const float2*>(l + 2 * i);
        lv[2 * i] = tl.x; lv[2 * i + 1] = tl.y;
    }

    // transposed label x-coord quirk: labels[b, x, y, 0]
    int cell = base_cell + tid;
    int b    = cell / (S * S);
    int rem  = cell - b * (S * S);
    int y    = rem / S;
    int x    = rem - y * S;
    int pc   = b * (S * S) + x * S + y;       // partner cell index
    float lb0;
    if (pc >= base_cell && pc < base_cell + NC) {
        lb0 = sl[(pc - base_cell) * C];
    } else {
        lb0 = labels[(size_t)pc * C];         // rare: image straddles block edge
    }

    float iou1 = iou_box(pv[0], pv[1], pv[2], pv[3], lb0, lv[1], lv[2], lv[3]);
    float iou2 = iou_box(pv[5], pv[6], pv[7], pv[8], lb0, lv[1], lv[2], lv[3]);

    float b1 = 5.0f * (sq(pv[0] - lv[0]) + sq(pv[1] - lv[1]))
             + sq(sqrtf(pv[2]) - sqrtf(lv[2])) + sq(sqrtf(pv[3]) - sqrtf(lv[3]))
             + sq(iou1 - pv[4])
             + 0.5f * pv[9] * pv[9];

    float b2 = 5.0f * (sq(pv[5] - lv[5]) + sq(pv[6] - lv[6]))
             + sq(sqrtf(pv[7]) - sqrtf(lv[7])) + sq(sqrtf(pv[8]) - sqrtf(lv[8]))
             + sq(iou2 - pv[9])
             + 0.5f * pv[4] * pv[4];

    float cls = 0.0f;
    #pragma unroll
    for (int c = 10; c < C; ++c) cls += sq(lv[c] - pv[c]);

    float obj_loss   = ((iou1 > iou2) ? b1 : b2) + cls;
    float noobj_loss = 0.5f * (pv[4] * pv[4] + pv[9] * pv[9]);
    float loss = (lv[4] == 1.0f) ? obj_loss : noobj_loss;

    // ---- reduction: wave shuffle -> LDS -> one store per block ----
    #pragma unroll
    for (int off = 32; off > 0; off >>= 1)
        loss += __shfl_down(loss, off, 64);

    __shared__ float wsum[BLOCK / 64];
    int lane = tid & 63;
    int wv   = tid >> 6;
    if (lane == 0) wsum[wv] = loss;
    __syncthreads();
    if (tid == 0) {
        partials[blockIdx.x] = wsum[0] + wsum[1] + wsum[2] + wsum[3];
    }
}

__global__ __launch_bounds__(BLOCK) void yolo_reduce_kernel(
        const float* __restrict__ partials,
        float* __restrict__ out) {
    const int tid = threadIdx.x;
    float s = 0.0f;
    for (int i = tid; i < NBLK; i += BLOCK) s += partials[i];

    #pragma unroll
    for (int off = 32; off > 0; off >>= 1)
        s += __shfl_down(s, off, 64);

    __shared__ float wsum[BLOCK / 64];
    int lane = tid & 63;
    int wv   = tid >> 6;
    if (lane == 0) wsum[wv] = s;
    __syncthreads();
    if (tid == 0) {
        out[0] = (wsum[0] + wsum[1] + wsum[2] + wsum[3]) * (1.0f / (float)BATCH);
    }
}

extern "C" void kernel_launch(void* const* d_in, const int* in_sizes, int n_in,
                              void* d_out, int out_size, void* d_ws, size_t ws_size,
                              hipStream_t stream) {
    const float* preds  = (const float*)d_in[0];
    const float* labels = (const float*)d_in[1];
    float* out = (float*)d_out;
    float* partials = (float*)d_ws;   // NBLK floats = 12.25 KB

    yolo_partial_kernel<<<NBLK, BLOCK, 0, stream>>>(preds, labels, partials);
    yolo_reduce_kernel<<<1, BLOCK, 0, stream>>>(partials, out);
}

// Round 4
// 204.998 us; speedup vs baseline: 1.0372x; 1.0192x over previous
//
#include <hip/hip_runtime.h>

// YOLO loss: preds (B,7,7,30) f32, labels (B,7,7,30) f32 -> scalar f32 (sum/B).
// R4: stage global->LDS via __builtin_amdgcn_global_load_lds (16B direct DMA,
// no VGPR roundtrip, no per-load vmcnt drain). Theory: R1-R3 were load-latency
// serialized; back-to-back DMA issues pipeline the full 60KB/block.

#define BATCH 16384
#define S 7
#define C 30
#define NCELLS (BATCH * S * S)   // 802816
#define BLOCK 256
#define NC 256                    // cells per block
#define NBLK (NCELLS / NC)        // 3136
#define F4_PER_ARR (NC * C / 4)   // 1920 float4 per array per block

#define GLOBAL_LOAD_LDS16(g, l)                                         \
    __builtin_amdgcn_global_load_lds(                                   \
        (const __attribute__((address_space(1))) void*)(g),             \
        (__attribute__((address_space(3))) void*)(l), 16, 0, 0)

__device__ __forceinline__ float sq(float v) { return v * v; }

__device__ __forceinline__ float iou_box(float acx, float acy, float aw, float ah,
                                         float bcx, float bcy, float bw, float bh) {
    float ax0 = acx - aw * 0.5f, ax1 = acx + aw * 0.5f;
    float ay0 = acy - ah * 0.5f, ay1 = acy + ah * 0.5f;
    float bx0 = bcx - bw * 0.5f, bx1 = bcx + bw * 0.5f;
    float by0 = bcy - bh * 0.5f, by1 = bcy + bh * 0.5f;
    float iw = fmaxf(fminf(ax1, bx1) - fmaxf(ax0, bx0), 0.0f);
    float ih = fmaxf(fminf(ay1, by1) - fmaxf(ay0, by0), 0.0f);
    float inter = iw * ih;
    float denom = aw * ah + bw * bh - inter + 1e-10f;
    return inter / denom;
}

__global__ __launch_bounds__(BLOCK) void yolo_partial_kernel(
        const float* __restrict__ preds,
        const float* __restrict__ labels,
        float* __restrict__ partials) {
    __shared__ __align__(16) float sp[NC * C];   // 30720 B
    __shared__ __align__(16) float sl[NC * C];   // 30720 B

    const int tid  = threadIdx.x;
    const int lane = tid & 63;
    const int wv   = tid >> 6;            // 4 waves
    const int base_cell = blockIdx.x * NC;

    const float4* gp = reinterpret_cast<const float4*>(preds  + (size_t)base_cell * C);
    const float4* gl = reinterpret_cast<const float4*>(labels + (size_t)base_cell * C);

    // ---- direct-to-LDS staging: wave w, step k covers float4 idx k*256+w*64+lane
    // 1920 float4 per array = 7 full steps (1792) + 128 tail (2 waves each array)
    #pragma unroll
    for (int k = 0; k < 7; ++k) {
        int f4 = k * 256 + wv * 64;                        // wave-uniform
        GLOBAL_LOAD_LDS16(gp + f4 + lane, (char*)sp + (size_t)f4 * 16);
        GLOBAL_LOAD_LDS16(gl + f4 + lane, (char*)sl + (size_t)f4 * 16);
    }
    if (wv < 2) {
        int f4 = 1792 + wv * 64;
        GLOBAL_LOAD_LDS16(gp + f4 + lane, (char*)sp + (size_t)f4 * 16);
    } else {
        int f4 = 1792 + (wv - 2) * 64;
        GLOBAL_LOAD_LDS16(gl + f4 + lane, (char*)sl + (size_t)f4 * 16);
    }
    __syncthreads();   // single vmcnt drain for all 15-16 DMA issues

    // ---- per-cell compute from LDS ----
    const float* p = sp + tid * C;
    const float* l = sl + tid * C;
    float pv[C], lv[C];
    #pragma unroll
    for (int i = 0; i < C / 2; ++i) {
        float2 tp = *reinterpret_cast<const float2*>(p + 2 * i);
        pv[2 * i] = tp.x; pv[2 * i + 1] = tp.y;
        float2 tl = *reinterpret_cast<const float2*>(l + 2 * i);
        lv[2 * i] = tl.x; lv[2 * i + 1] = tl.y;
    }

    // transposed label x-coord quirk: labels[b, x, y, 0]
    int cell = base_cell + tid;
    int b    = cell / (S * S);
    int rem  = cell - b * (S * S);
    int y    = rem / S;
    int x    = rem - y * S;
    int pc   = b * (S * S) + x * S + y;       // partner cell index
    float lb0;
    if (pc >= base_cell && pc < base_cell + NC) {
        lb0 = sl[(pc - base_cell) * C];
    } else {
        lb0 = labels[(size_t)pc * C];         // rare: image straddles block edge
    }

    float iou1 = iou_box(pv[0], pv[1], pv[2], pv[3], lb0, lv[1], lv[2], lv[3]);
    float iou2 = iou_box(pv[5], pv[6], pv[7], pv[8], lb0, lv[1], lv[2], lv[3]);

    float b1 = 5.0f * (sq(pv[0] - lv[0]) + sq(pv[1] - lv[1]))
             + sq(sqrtf(pv[2]) - sqrtf(lv[2])) + sq(sqrtf(pv[3]) - sqrtf(lv[3]))
             + sq(iou1 - pv[4])
             + 0.5f * pv[9] * pv[9];

    float b2 = 5.0f * (sq(pv[5] - lv[5]) + sq(pv[6] - lv[6]))
             + sq(sqrtf(pv[7]) - sqrtf(lv[7])) + sq(sqrtf(pv[8]) - sqrtf(lv[8]))
             + sq(iou2 - pv[9])
             + 0.5f * pv[4] * pv[4];

    float cls = 0.0f;
    #pragma unroll
    for (int c = 10; c < C; ++c) cls += sq(lv[c] - pv[c]);

    float obj_loss   = ((iou1 > iou2) ? b1 : b2) + cls;
    float noobj_loss = 0.5f * (pv[4] * pv[4] + pv[9] * pv[9]);
    float loss = (lv[4] == 1.0f) ? obj_loss : noobj_loss;

    // ---- reduction: wave shuffle -> LDS -> one store per block ----
    #pragma unroll
    for (int off = 32; off > 0; off >>= 1)
        loss += __shfl_down(loss, off, 64);

    __shared__ float wsum[BLOCK / 64];
    if (lane == 0) wsum[wv] = loss;
    __syncthreads();
    if (tid == 0) {
        partials[blockIdx.x] = wsum[0] + wsum[1] + wsum[2] + wsum[3];
    }
}

__global__ __launch_bounds__(BLOCK) void yolo_reduce_kernel(
        const float* __restrict__ partials,
        float* __restrict__ out) {
    const int tid = threadIdx.x;
    float s = 0.0f;
    for (int i = tid; i < NBLK; i += BLOCK) s += partials[i];

    #pragma unroll
    for (int off = 32; off > 0; off >>= 1)
        s += __shfl_down(s, off, 64);

    __shared__ float wsum[BLOCK / 64];
    int lane = tid & 63;
    int wv   = tid >> 6;
    if (lane == 0) wsum[wv] = s;
    __syncthreads();
    if (tid == 0) {
        out[0] = (wsum[0] + wsum[1] + wsum[2] + wsum[3]) * (1.0f / (float)BATCH);
    }
}

extern "C" void kernel_launch(void* const* d_in, const int* in_sizes, int n_in,
                              void* d_out, int out_size, void* d_ws, size_t ws_size,
                              hipStream_t stream) {
    const float* preds  = (const float*)d_in[0];
    const float* labels = (const float*)d_in[1];
    float* out = (float*)d_out;
    float* partials = (float*)d_ws;   // NBLK floats = 12.25 KB

    yolo_partial_kernel<<<NBLK, BLOCK, 0, stream>>>(preds, labels, partials);
    yolo_reduce_kernel<<<1, BLOCK, 0, stream>>>(partials, out);
}